// Round 1
// baseline (599.420 us; speedup 1.0000x reference)
//
#include <hip/hip_runtime.h>

#define KMASK (-2.3819763e38f)

typedef __attribute__((ext_vector_type(8))) _Float16 f16x8;
typedef __attribute__((ext_vector_type(4))) _Float16 f16x4;
typedef __attribute__((ext_vector_type(4))) float f32x4;

// async global->LDS, 16B per lane. LDS dest must be wave-uniform base (+lane*16 implicit).
__device__ __forceinline__ void gload_lds16(const void* g, void* lds) {
    __builtin_amdgcn_global_load_lds(
        (__attribute__((address_space(1))) void*)(g),
        (__attribute__((address_space(3))) void*)(lds), 16, 0, 0);
}

// ---------------------------------------------------------------------------
// RoPE table: ct/st[s][f] = cos/sin(s * theta^(-2f/256)), f in [0,128)
// ---------------------------------------------------------------------------
__global__ void rope_tab(float* __restrict__ ct, float* __restrict__ st) {
    const int s = blockIdx.x, f = threadIdx.x;
    const float inv = powf(10000.f, -2.f * (float)f / 256.f);
    const float a = (float)s * inv;
    ct[s * 128 + f] = cosf(a);
    st[s * 128 + f] = sinf(a);
}

// ---------------------------------------------------------------------------
// f32 -> f16 elementwise (4/thread)
// ---------------------------------------------------------------------------
__global__ void conv16(const float* __restrict__ x, _Float16* __restrict__ y) {
    const size_t i = ((size_t)blockIdx.x * 256 + threadIdx.x) * 4;
    const float4 v = *(const float4*)(x + i);
    f16x4 o;
    o.x = (_Float16)v.x; o.y = (_Float16)v.y; o.z = (_Float16)v.z; o.w = (_Float16)v.w;
    *(f16x4*)(y + i) = o;
}

// ---------------------------------------------------------------------------
// Tiled transpose + convert: W[K][N] f32 -> WT[N][K] f16
// block (32,8), grid (N/32, K/32)
// ---------------------------------------------------------------------------
__global__ void tconv(const float* __restrict__ W, _Float16* __restrict__ WT, int K, int N) {
    __shared__ float t[32][33];
    const int n0 = blockIdx.x * 32, k0 = blockIdx.y * 32;
    const int tx = threadIdx.x, ty = threadIdx.y;
#pragma unroll
    for (int i = ty; i < 32; i += 8) t[i][tx] = W[(size_t)(k0 + i) * N + n0 + tx];
    __syncthreads();
#pragma unroll
    for (int i = ty; i < 32; i += 8) WT[(size_t)(n0 + i) * K + k0 + tx] = (_Float16)t[tx][i];
}

// ---------------------------------------------------------------------------
// GEMM: C[M][N] (f32) = A[M][K] (f16, row-major) @ BT[N][K]^T (f16)
// 128x128 tile, BK=32, 4 waves (2x2), 16x16x32 MFMA, global_load_lds staging.
// ---------------------------------------------------------------------------
__global__ __launch_bounds__(256) void gemm_f16(
    const _Float16* __restrict__ A, const _Float16* __restrict__ BT,
    float* __restrict__ C, int M, int N, int K) {
    __shared__ _Float16 As[128 * 32];
    __shared__ _Float16 Bs[128 * 32];
    const int tid = threadIdx.x;
    const int l = tid & 63, w = tid >> 6;
    const int lr = l & 15, lg4 = l >> 4;
    const int wr = w >> 1, wc = w & 1;
    const size_t bm = (size_t)blockIdx.y * 128, bn = (size_t)blockIdx.x * 128;

    f32x4 acc[4][4];
#pragma unroll
    for (int i = 0; i < 4; i++)
#pragma unroll
        for (int j = 0; j < 4; j++) acc[i][j] = (f32x4){0.f, 0.f, 0.f, 0.f};

    for (int k0 = 0; k0 < K; k0 += 32) {
#pragma unroll
        for (int i = 0; i < 2; i++) {
            const int o = w * 2048 + i * 1024 + l * 16;  // byte offset into 8KB tile
            const int row = o >> 6;                      // 64B per LDS row (32 f16)
            const int ce = (o & 63) >> 1;                // element within row
            gload_lds16(A + (bm + row) * (size_t)K + k0 + ce, (char*)As + (o - l * 16));
            gload_lds16(BT + (bn + row) * (size_t)K + k0 + ce, (char*)Bs + (o - l * 16));
        }
        asm volatile("s_waitcnt vmcnt(0)" ::: "memory");
        __syncthreads();

        f16x8 af[4], bfr[4];
#pragma unroll
        for (int mm = 0; mm < 4; mm++)
            af[mm] = *(const f16x8*)(As + (wr * 64 + mm * 16 + lr) * 32 + lg4 * 8);
#pragma unroll
        for (int nn = 0; nn < 4; nn++)
            bfr[nn] = *(const f16x8*)(Bs + (wc * 64 + nn * 16 + lr) * 32 + lg4 * 8);
#pragma unroll
        for (int mm = 0; mm < 4; mm++)
#pragma unroll
            for (int nn = 0; nn < 4; nn++)
                acc[mm][nn] = __builtin_amdgcn_mfma_f32_16x16x32_f16(af[mm], bfr[nn], acc[mm][nn], 0, 0, 0);
        __syncthreads();
    }
#pragma unroll
    for (int mm = 0; mm < 4; mm++)
#pragma unroll
        for (int nn = 0; nn < 4; nn++)
#pragma unroll
            for (int r = 0; r < 4; r++) {
                const size_t rr = bm + wr * 64 + mm * 16 + lg4 * 4 + r;
                const size_t cc = bn + wc * 64 + nn * 16 + lr;
                C[rr * N + cc] = acc[mm][nn][r];
            }
}

// ---------------------------------------------------------------------------
// RMSNorm (+optional (1+scale)) (+optional RoPE). One wave per (s,h) row of 256.
// x layout: [s][H*256]. out layout: [h][s][256] (head-major, f16).
// ---------------------------------------------------------------------------
__global__ __launch_bounds__(256) void norm_rope(
    const float* __restrict__ x, const float* __restrict__ scale,
    const float* __restrict__ ct, const float* __restrict__ st,
    _Float16* __restrict__ out, int H, int do_rope) {
    const int w = threadIdx.x >> 6, l = threadIdx.x & 63;
    const int row = blockIdx.x * 4 + w;
    const int s = row / H, h = row % H;
    const float4 v = *(const float4*)(x + (size_t)row * 256 + l * 4);
    float ss = v.x * v.x + v.y * v.y + v.z * v.z + v.w * v.w;
#pragma unroll
    for (int mm = 1; mm < 64; mm <<= 1) ss += __shfl_xor(ss, mm);
    const float r = rsqrtf(ss * (1.f / 256.f) + 1e-6f);
    float y0, y1, y2, y3;
    if (scale) {
        const float4 sc = *(const float4*)(scale + l * 4);
        y0 = v.x * r * (1.f + sc.x); y1 = v.y * r * (1.f + sc.y);
        y2 = v.z * r * (1.f + sc.z); y3 = v.w * r * (1.f + sc.w);
    } else {
        y0 = v.x * r; y1 = v.y * r; y2 = v.z * r; y3 = v.w * r;
    }
    if (do_rope) {
        const float p0 = __shfl_xor(y0, 32), p1 = __shfl_xor(y1, 32);
        const float p2 = __shfl_xor(y2, 32), p3 = __shfl_xor(y3, 32);
        const int f = (l & 31) * 4;
        const float4 c = *(const float4*)(ct + (size_t)s * 128 + f);
        const float4 sn = *(const float4*)(st + (size_t)s * 128 + f);
        if (l < 32) {  // d < 128: x1*cos - x2*sin
            y0 = y0 * c.x - p0 * sn.x; y1 = y1 * c.y - p1 * sn.y;
            y2 = y2 * c.z - p2 * sn.z; y3 = y3 * c.w - p3 * sn.w;
        } else {       // d >= 128: x2*cos + x1*sin
            y0 = y0 * c.x + p0 * sn.x; y1 = y1 * c.y + p1 * sn.y;
            y2 = y2 * c.z + p2 * sn.z; y3 = y3 * c.w + p3 * sn.w;
        }
    }
    f16x4 o;
    o.x = (_Float16)y0; o.y = (_Float16)y1; o.z = (_Float16)y2; o.w = (_Float16)y3;
    *(f16x4*)(out + ((size_t)h * 4096 + s) * 256 + l * 4) = o;
}

// ---------------------------------------------------------------------------
// Flash attention: GQA (NH=8, NKV=4), sliding window 1024, tanh softcap 50.
// Grid (S/64, NH); block 256 = 4 waves, wave w owns q rows qs+w*16 .. +15.
// q/k/v in head-major f16 [h][s][256]. Output attn[s][h*256+d] f16.
// ---------------------------------------------------------------------------
__global__ __launch_bounds__(256) void attn_fwd(
    const _Float16* __restrict__ qn, const _Float16* __restrict__ kn,
    const _Float16* __restrict__ vn, _Float16* __restrict__ attnout) {
    __shared__ _Float16 Vs[32 * 256];
    __shared__ _Float16 Ps[4][16 * 32];
    const int tid = threadIdx.x, l = tid & 63, w = tid >> 6;
    const int lr = l & 15, lg4 = l >> 4;
    const int h = blockIdx.y, kvh = h >> 1;
    const int qs = blockIdx.x * 64;

    // Q fragments for this wave's 16 rows (whole D=256 in registers)
    f16x8 qfr[8];
    {
        const _Float16* qp = qn + ((size_t)h * 4096 + qs + w * 16 + lr) * 256 + lg4 * 8;
#pragma unroll
        for (int c = 0; c < 8; c++) qfr[c] = *(const f16x8*)(qp + c * 32);
    }
    f32x4 Of[16];
#pragma unroll
    for (int i = 0; i < 16; i++) Of[i] = (f32x4){0.f, 0.f, 0.f, 0.f};
    float m[4], lsum[4];
#pragma unroll
    for (int r = 0; r < 4; r++) { m[r] = KMASK; lsum[r] = 0.f; }

    const int kt0 = (qs >= 1024) ? ((qs - 1023) & ~31) : 0;
    for (int kt = kt0; kt < qs + 64; kt += 32) {
        // stage V tile [32][256] linearly (coalesced both sides)
#pragma unroll
        for (int p = 0; p < 4; p++) {
            const int row = (tid >> 5) + p * 8, d0 = (tid & 31) * 8;
            *(f16x8*)(Vs + row * 256 + d0) =
                *(const f16x8*)(vn + ((size_t)kvh * 4096 + kt + row) * 256 + d0);
        }
        __syncthreads();

        // QK^T: 2 key sub-tiles x 8 d-chunks
        f32x4 lgf[2];
        lgf[0] = (f32x4){0.f, 0.f, 0.f, 0.f};
        lgf[1] = (f32x4){0.f, 0.f, 0.f, 0.f};
        const _Float16* kp = kn + ((size_t)kvh * 4096 + kt + lr) * 256 + lg4 * 8;
#pragma unroll
        for (int c = 0; c < 8; c++) {
            const f16x8 k0f = *(const f16x8*)(kp + c * 32);
            const f16x8 k1f = *(const f16x8*)(kp + 16 * 256 + c * 32);
            lgf[0] = __builtin_amdgcn_mfma_f32_16x16x32_f16(qfr[c], k0f, lgf[0], 0, 0, 0);
            lgf[1] = __builtin_amdgcn_mfma_f32_16x16x32_f16(qfr[c], k1f, lgf[1], 0, 0, 0);
        }

        // softcap + mask + online softmax. logits row = (lg4*4+r), col = lr (+16)
        float p8[8], sc[4];
#pragma unroll
        for (int r = 0; r < 4; r++) {
            const int srow = qs + w * 16 + lg4 * 4 + r;
            float c0 = tanhf(lgf[0][r] * 0.02f) * 50.f;
            float c1 = tanhf(lgf[1][r] * 0.02f) * 50.f;
            const int t0 = kt + lr, t1 = t0 + 16;
            const bool v0 = (t0 <= srow) && (srow - t0 < 1024);
            const bool v1 = (t1 <= srow) && (srow - t1 < 1024);
            c0 = v0 ? c0 : KMASK;
            c1 = v1 ? c1 : KMASK;
            float best = fmaxf(c0, c1);
#pragma unroll
            for (int mm = 1; mm < 16; mm <<= 1) best = fmaxf(best, __shfl_xor(best, mm));
            const float newm = fmaxf(m[r], best);
            const float scale = __expf(m[r] - newm);
            const float p0 = v0 ? __expf(c0 - newm) : 0.f;  // explicit 0 for masked
            const float p1 = v1 ? __expf(c1 - newm) : 0.f;
            float ps = p0 + p1;
#pragma unroll
            for (int mm = 1; mm < 16; mm <<= 1) ps += __shfl_xor(ps, mm);
            lsum[r] = lsum[r] * scale + ps;
            m[r] = newm;
            sc[r] = scale;
            p8[r] = p0;
            p8[4 + r] = p1;
        }
#pragma unroll
        for (int i = 0; i < 16; i++) {
            f32x4 o = Of[i];
            o[0] *= sc[0]; o[1] *= sc[1]; o[2] *= sc[2]; o[3] *= sc[3];
            Of[i] = o;
        }

        // P (f16) -> per-wave LDS, re-layout D-frag -> A-frag
        _Float16* pw = &Ps[w][0];
#pragma unroll
        for (int r = 0; r < 4; r++) {
            pw[(lg4 * 4 + r) * 32 + lr] = (_Float16)p8[r];
            pw[(lg4 * 4 + r) * 32 + lr + 16] = (_Float16)p8[4 + r];
        }
        asm volatile("s_waitcnt lgkmcnt(0)" ::: "memory");
        const f16x8 pf = *(const f16x8*)(pw + lr * 32 + lg4 * 8);

        // PV: 16 d-chunks
#pragma unroll
        for (int dc = 0; dc < 16; dc++) {
            f16x8 vfr;
#pragma unroll
            for (int j = 0; j < 8; j++) vfr[j] = Vs[(lg4 * 8 + j) * 256 + dc * 16 + lr];
            Of[dc] = __builtin_amdgcn_mfma_f32_16x16x32_f16(pf, vfr, Of[dc], 0, 0, 0);
        }
        __syncthreads();
    }

    float inv[4];
#pragma unroll
    for (int r = 0; r < 4; r++) inv[r] = 1.f / lsum[r];
#pragma unroll
    for (int dc = 0; dc < 16; dc++)
#pragma unroll
        for (int r = 0; r < 4; r++) {
            const size_t srow = qs + w * 16 + lg4 * 4 + r;
            attnout[srow * 2048 + h * 256 + dc * 16 + lr] = (_Float16)(Of[dc][r] * inv[r]);
        }
}

// ---------------------------------------------------------------------------
extern "C" void kernel_launch(void* const* d_in, const int* in_sizes, int n_in,
                              void* d_out, int out_size, void* d_ws, size_t ws_size,
                              hipStream_t stream) {
    (void)in_sizes; (void)n_in; (void)out_size; (void)ws_size;
    const float* hidden  = (const float*)d_in[0];
    const float* Wq      = (const float*)d_in[1];
    const float* Wk      = (const float*)d_in[2];
    const float* Wv      = (const float*)d_in[3];
    const float* Wo      = (const float*)d_in[4];
    const float* q_scale = (const float*)d_in[5];
    const float* k_scale = (const float*)d_in[6];

    char* ws = (char*)d_ws;
    size_t off = 0;
    auto carve = [&](size_t bytes) -> char* {
        char* p = ws + off;
        off += (bytes + 255) & ~(size_t)255;
        return p;
    };
    _Float16* Hh    = (_Float16*)carve((size_t)4096 * 2048 * 2);
    _Float16* WqT   = (_Float16*)carve((size_t)2048 * 2048 * 2);
    _Float16* WkT   = (_Float16*)carve((size_t)1024 * 2048 * 2);
    _Float16* WvT   = (_Float16*)carve((size_t)1024 * 2048 * 2);
    _Float16* WoT   = (_Float16*)carve((size_t)2048 * 2048 * 2);
    float*    qf    = (float*)carve((size_t)4096 * 2048 * 4);
    float*    kf    = (float*)carve((size_t)4096 * 1024 * 4);
    float*    vf    = (float*)carve((size_t)4096 * 1024 * 4);
    _Float16* qn    = (_Float16*)carve((size_t)8 * 4096 * 256 * 2);
    _Float16* kn    = (_Float16*)carve((size_t)4 * 4096 * 256 * 2);
    _Float16* vnb   = (_Float16*)carve((size_t)4 * 4096 * 256 * 2);
    _Float16* attnb = (_Float16*)carve((size_t)4096 * 2048 * 2);
    float*    ct    = (float*)carve((size_t)4096 * 128 * 4);
    float*    stb   = (float*)carve((size_t)4096 * 128 * 4);

    rope_tab<<<dim3(4096), dim3(128), 0, stream>>>(ct, stb);
    conv16<<<dim3(8192), dim3(256), 0, stream>>>(hidden, Hh);
    tconv<<<dim3(64, 64), dim3(32, 8), 0, stream>>>(Wq, WqT, 2048, 2048);
    tconv<<<dim3(32, 64), dim3(32, 8), 0, stream>>>(Wk, WkT, 2048, 1024);
    tconv<<<dim3(32, 64), dim3(32, 8), 0, stream>>>(Wv, WvT, 2048, 1024);
    tconv<<<dim3(64, 64), dim3(32, 8), 0, stream>>>(Wo, WoT, 2048, 2048);

    gemm_f16<<<dim3(16, 32), dim3(256), 0, stream>>>(Hh, WqT, qf, 4096, 2048, 2048);
    gemm_f16<<<dim3(8, 32), dim3(256), 0, stream>>>(Hh, WkT, kf, 4096, 1024, 2048);
    gemm_f16<<<dim3(8, 32), dim3(256), 0, stream>>>(Hh, WvT, vf, 4096, 1024, 2048);

    norm_rope<<<dim3(8192), dim3(256), 0, stream>>>(qf, q_scale, ct, stb, qn, 8, 1);
    norm_rope<<<dim3(4096), dim3(256), 0, stream>>>(kf, k_scale, ct, stb, kn, 4, 1);
    norm_rope<<<dim3(4096), dim3(256), 0, stream>>>(vf, nullptr, ct, stb, vnb, 4, 0);

    attn_fwd<<<dim3(64, 8), dim3(256), 0, stream>>>(qn, kn, vnb, attnb);

    gemm_f16<<<dim3(16, 32), dim3(256), 0, stream>>>(attnb, WoT, (float*)d_out, 4096, 2048, 2048);
}